// Round 2
// baseline (662.213 us; speedup 1.0000x reference)
//
#include <hip/hip_runtime.h>
#include <hip/hip_bf16.h>

#define NQ 12
#define NL 5
#define DIM 4096
#define BATCH 4096
#define TILE 128
#define BK 32
#define NIT (DIM / BK)                  // 128
#define NTILE (BATCH / TILE)            // 32
#define NBLK (NTILE * (NTILE + 1) / 2)  // 528
#define NMAIN 512                       // balanced main grid (2 per CU exactly)
#define NLEFT (NBLK - NMAIN)            // 16 leftover tiles
#define SLICE_IT (NIT / 32)             // 4 iters per slice, 32 slices/leftover

typedef __bf16 bf16x8 __attribute__((ext_vector_type(8)));
typedef float f32x16 __attribute__((ext_vector_type(16)));
typedef unsigned int u32x4 __attribute__((ext_vector_type(4)));
typedef unsigned int u32;
typedef unsigned short u16;

#define MFMA32(a, b, c) __builtin_amdgcn_mfma_f32_32x32x16_bf16(a, b, c, 0, 0, 0)

// float -> bf16 bits, round-to-nearest-even
__device__ static inline u16 f32_to_bf16_bits(float x) {
    u32 b = __builtin_bit_cast(u32, x);
    b += 0x7fffu + ((b >> 16) & 1u);
    return (u16)(b >> 16);
}

// async 16B global->LDS; HW writes wave-uniform lds base + lane*16.
__device__ static inline void async_copy16(const void* g, void* l) {
    __builtin_amdgcn_global_load_lds((const __attribute__((address_space(1))) u32*)g,
                                     (__attribute__((address_space(3))) u32*)l, 16, 0, 0);
}

// complex helpers
__device__ static inline float2 cmul(float2 m, float2 a) {
    return make_float2(m.x * a.x - m.y * a.y, m.x * a.y + m.y * a.x);
}
__device__ static inline float2 cadd(float2 a, float2 b) {
    return make_float2(a.x + b.x, a.y + b.y);
}

// tile index p (0..527) -> (bi, bj), bi <= bj
__device__ static inline void tile_of(int p, int* bi, int* bj) {
    int rem = p, b = 0;
    while (rem >= NTILE - b) { rem -= NTILE - b; ++b; }
    *bi = b; *bj = b + rem;
}

// ---------------------------------------------------------------------------
// Kernel A: batch-independent part (layers 0..3 full, layer 4 param gates).
// ---------------------------------------------------------------------------
__global__ __launch_bounds__(1024) void qnn_base(const float* __restrict__ params,
                                                 float2* __restrict__ psi1) {
    __shared__ float2 st[DIM];
    __shared__ float2 U[NL * NQ][4];
    const int t = threadIdx.x;

    for (int k = t; k < DIM; k += 1024) st[k] = make_float2(k == 0 ? 1.f : 0.f, 0.f);

    if (t < NL * NQ) {
        float phi = params[t * 3 + 0], th = params[t * 3 + 1], lam = params[t * 3 + 2];
        float c = cosf(0.5f * th), s = sinf(0.5f * th);
        float ap = 0.5f * (lam + phi), am = 0.5f * (lam - phi);
        // M = U^T, U = Rz(lam) Ry(th) Rz(phi)
        U[t][0] = make_float2(c * cosf(ap), -c * sinf(ap));
        U[t][1] = make_float2(s * cosf(am), s * sinf(am));
        U[t][2] = make_float2(-s * cosf(am), s * sinf(am));
        U[t][3] = make_float2(c * cosf(ap), c * sinf(ap));
    }
    __syncthreads();

    for (int l = 0; l < NL; ++l) {
        for (int qq = 0; qq < NQ; qq += 2) {
            const float2* M1 = U[l * NQ + qq];
            const float2* M2 = U[l * NQ + qq + 1];
            const int b2 = 10 - qq;              // bit of qubit qq+1
            const int s2 = 1 << b2, s1 = s2 << 1;
            int hi = t >> b2, lo = t & (s2 - 1);
            int i00 = (hi << (b2 + 2)) | lo;
            int i01 = i00 + s2, i10 = i00 + s1, i11 = i10 + s2;
            float2 a00 = st[i00], a01 = st[i01], a10 = st[i10], a11 = st[i11];
            float2 b00 = cadd(cmul(M1[0], a00), cmul(M1[1], a10));
            float2 b10 = cadd(cmul(M1[2], a00), cmul(M1[3], a10));
            float2 b01 = cadd(cmul(M1[0], a01), cmul(M1[1], a11));
            float2 b11 = cadd(cmul(M1[2], a01), cmul(M1[3], a11));
            st[i00] = cadd(cmul(M2[0], b00), cmul(M2[1], b01));
            st[i01] = cadd(cmul(M2[2], b00), cmul(M2[3], b01));
            st[i10] = cadd(cmul(M2[0], b10), cmul(M2[1], b11));
            st[i11] = cadd(cmul(M2[2], b10), cmul(M2[3], b11));
            __syncthreads();
        }
        if (l < NL - 1) {
            float2 v[4];
            #pragma unroll
            for (int u = 0; u < 4; ++u) {
                int k = t * 4 + u, j = k;
                #pragma unroll
                for (int q = 10; q >= 0; --q) j ^= ((j >> (11 - q)) & 1) << (10 - q);
                v[u] = st[j];
            }
            __syncthreads();
            #pragma unroll
            for (int u = 0; u < 4; ++u) st[t * 4 + u] = v[u];
            __syncthreads();
        }
    }
    for (int k = t; k < DIM; k += 1024) psi1[k] = st[k];
}

// ---------------------------------------------------------------------------
// Kernel B: per-batch data gates. The final CNOT-chain/bit-reverse output
// permutation is DROPPED: it is a fixed column permutation of S and
// K = |S S^H|^2 is invariant under column permutations.
// Blocks 0..15 additionally zero the K regions of the 16 leftover tiles
// (slice partials accumulate there via atomicAdd in qnn_gram; kernel-boundary
// ordering makes the zeros visible).
// ---------------------------------------------------------------------------
__global__ __launch_bounds__(1024) void qnn_states(const float* __restrict__ X,
                                                   const float2* __restrict__ psi1,
                                                   u16* __restrict__ R,
                                                   u16* __restrict__ I,
                                                   float* __restrict__ K) {
    __shared__ float2 st[DIM];
    __shared__ float cs[NQ], sn[NQ];
    const int b = blockIdx.x;
    const int t = threadIdx.x;

    for (int k = t; k < DIM; k += 1024) st[k] = psi1[k];
    if (t < NQ) {
        float a = 0.5f * X[b * NQ + t];
        cs[t] = cosf(a); sn[t] = sinf(a);
    }
    __syncthreads();

    for (int qq = 0; qq < NQ; qq += 2) {
        const float c1 = cs[qq], s1v = sn[qq];
        const float c2 = cs[qq + 1], s2v = sn[qq + 1];
        const int b2 = 10 - qq;
        const int s2 = 1 << b2, s1 = s2 << 1;
        int hi = t >> b2, lo = t & (s2 - 1);
        int i00 = (hi << (b2 + 2)) | lo;
        int i01 = i00 + s2, i10 = i00 + s1, i11 = i10 + s2;
        float2 a00 = st[i00], a01 = st[i01], a10 = st[i10], a11 = st[i11];
        float2 b00 = make_float2(c1 * a00.x + s1v * a10.x, c1 * a00.y + s1v * a10.y);
        float2 b10 = make_float2(-s1v * a00.x + c1 * a10.x, -s1v * a00.y + c1 * a10.y);
        float2 b01 = make_float2(c1 * a01.x + s1v * a11.x, c1 * a01.y + s1v * a11.y);
        float2 b11 = make_float2(-s1v * a01.x + c1 * a11.x, -s1v * a01.y + c1 * a11.y);
        st[i00] = make_float2(c2 * b00.x + s2v * b01.x, c2 * b00.y + s2v * b01.y);
        st[i01] = make_float2(-s2v * b00.x + c2 * b01.x, -s2v * b00.y + c2 * b01.y);
        st[i10] = make_float2(c2 * b10.x + s2v * b11.x, c2 * b10.y + s2v * b11.y);
        st[i11] = make_float2(-s2v * b10.x + c2 * b11.x, -s2v * b10.y + c2 * b11.y);
        __syncthreads();
    }

    u16 hr[4], hi4[4];
    #pragma unroll
    for (int u = 0; u < 4; ++u) {
        float2 a = st[t * 4 + u];
        hr[u] = f32_to_bf16_bits(a.x);
        hi4[u] = f32_to_bf16_bits(a.y);
    }
    *(ushort4*)&R[(size_t)b * DIM + t * 4] = make_ushort4(hr[0], hr[1], hr[2], hr[3]);
    *(ushort4*)&I[(size_t)b * DIM + t * 4] = make_ushort4(hi4[0], hi4[1], hi4[2], hi4[3]);

    if (b < NLEFT) {
        int bi2, bj2;
        tile_of(NMAIN + b, &bi2, &bj2);
        const int biT = bi2 * TILE, bjT = bj2 * TILE;
        const float4 z = make_float4(0.f, 0.f, 0.f, 0.f);
        for (int e = t; e < (TILE * TILE) / 4; e += 1024) {
            int il = e >> 5, c4 = (e & 31) * 4;
            *(float4*)&K[(size_t)(biT + il) * BATCH + bjT + c4] = z;
            if (bi2 != bj2)
                *(float4*)&K[(size_t)(bjT + il) * BATCH + biT + c4] = z;
        }
    }
}

// ---------------------------------------------------------------------------
// Gram inner machinery: BK=32, double-buffered LDS (2 x 32KB), counted-drain
// 2-phase pipeline (T3/T4): read g1 || ISSUE(next->other buf) -> MFMA g0 ->
// MFMA g1 -> vmcnt(0) [covered by full iter of MFMA] -> raw s_barrier ->
// prefetch g0 of next buffer.
// LDS layout per buffer: 4 planes [A-Re, A-Im, B-Re, B-Im][128 rows][64 B];
// chunk swizzle phys = logchunk ^ ((row>>1)&3) (R1/R4-verified).
// ---------------------------------------------------------------------------
__device__ __forceinline__ void gram_accum(
    const u16* __restrict__ Rm, const u16* __restrict__ Im,
    int rowA, int rowB, int it0, int itN,
    unsigned char (&lds)[2][4][TILE][64],
    f32x16 (&accRe)[2][2], f32x16 (&accIm)[2][2],
    int w, int lane) {
    const int half = lane >> 5, l31 = lane & 31;
    const int wm = (w >> 1) * 64, wn = (w & 1) * 64;
    const int srow16 = lane >> 2, sphys = lane & 3;

    bf16x8 fRA[2][2], fIA[2][2], fRB[2][2], fIB[2][2];

#define ISSUE(itx, c)                                                                    \
    do {                                                                                 \
        const size_t kb = (size_t)(itx) * 64;                                            \
        _Pragma("unroll")                                                                \
        for (int pl = 0; pl < 4; ++pl) {                                                 \
            const u16* srcp = (pl & 1) ? Im : Rm;                                        \
            const int rb = (pl < 2) ? rowA : rowB;                                       \
            _Pragma("unroll")                                                            \
            for (int jj = 0; jj < 2; ++jj) {                                             \
                const int s = w * 2 + jj;                                                \
                const int row = s * 16 + srow16;                                         \
                const int logc = sphys ^ ((row >> 1) & 3);                               \
                const char* gpp = (const char*)srcp + (size_t)(rb + row) * (DIM * 2)     \
                                  + kb + (size_t)logc * 16;                              \
                char* lp = (char*)&lds[c][pl][0][0] + (size_t)s * 1024;                  \
                async_copy16(gpp, lp);                                                   \
            }                                                                            \
        }                                                                                \
    } while (0)

#define READF(g, c)                                                                      \
    do {                                                                                 \
        _Pragma("unroll")                                                                \
        for (int mi = 0; mi < 2; ++mi) {                                                 \
            const int r = wm + mi * 32 + l31;                                            \
            const int ph = ((g) * 2 + half) ^ ((r >> 1) & 3);                            \
            fRA[g][mi] = *(const bf16x8*)&lds[c][0][r][ph * 16];                         \
            fIA[g][mi] = *(const bf16x8*)&lds[c][1][r][ph * 16];                         \
        }                                                                                \
        _Pragma("unroll")                                                                \
        for (int ni = 0; ni < 2; ++ni) {                                                 \
            const int r = wn + ni * 32 + l31;                                            \
            const int ph = ((g) * 2 + half) ^ ((r >> 1) & 3);                            \
            fRB[g][ni] = *(const bf16x8*)&lds[c][2][r][ph * 16];                         \
            fIB[g][ni] = *(const bf16x8*)&lds[c][3][r][ph * 16];                         \
        }                                                                                \
    } while (0)

#define MGROUP(g)                                                                        \
    do {                                                                                 \
        bf16x8 fRAn0, fRAn1;                                                             \
        { u32x4 t0 = __builtin_bit_cast(u32x4, fRA[g][0]) ^ 0x80008000u;                 \
          fRAn0 = __builtin_bit_cast(bf16x8, t0); }                                      \
        { u32x4 t1 = __builtin_bit_cast(u32x4, fRA[g][1]) ^ 0x80008000u;                 \
          fRAn1 = __builtin_bit_cast(bf16x8, t1); }                                      \
        accRe[0][0] = MFMA32(fRA[g][0], fRB[g][0], accRe[0][0]);                         \
        accRe[0][1] = MFMA32(fRA[g][0], fRB[g][1], accRe[0][1]);                         \
        accRe[1][0] = MFMA32(fRA[g][1], fRB[g][0], accRe[1][0]);                         \
        accRe[1][1] = MFMA32(fRA[g][1], fRB[g][1], accRe[1][1]);                         \
        accIm[0][0] = MFMA32(fIA[g][0], fRB[g][0], accIm[0][0]);                         \
        accIm[0][1] = MFMA32(fIA[g][0], fRB[g][1], accIm[0][1]);                         \
        accIm[1][0] = MFMA32(fIA[g][1], fRB[g][0], accIm[1][0]);                         \
        accIm[1][1] = MFMA32(fIA[g][1], fRB[g][1], accIm[1][1]);                         \
        accRe[0][0] = MFMA32(fIA[g][0], fIB[g][0], accRe[0][0]);                         \
        accRe[0][1] = MFMA32(fIA[g][0], fIB[g][1], accRe[0][1]);                         \
        accRe[1][0] = MFMA32(fIA[g][1], fIB[g][0], accRe[1][0]);                         \
        accRe[1][1] = MFMA32(fIA[g][1], fIB[g][1], accRe[1][1]);                         \
        accIm[0][0] = MFMA32(fRAn0, fIB[g][0], accIm[0][0]);                             \
        accIm[0][1] = MFMA32(fRAn0, fIB[g][1], accIm[0][1]);                             \
        accIm[1][0] = MFMA32(fRAn1, fIB[g][0], accIm[1][0]);                             \
        accIm[1][1] = MFMA32(fRAn1, fIB[g][1], accIm[1][1]);                             \
    } while (0)

    ISSUE(it0, 0);
    asm volatile("s_waitcnt vmcnt(0)\ns_barrier" ::: "memory");
    READF(0, 0);
    for (int it = it0; it < itN; ++it) {
        const int c = (it - it0) & 1;
        READF(1, c);
        if (it + 1 < itN) ISSUE(it + 1, c ^ 1);
        __builtin_amdgcn_s_setprio(1);
        MGROUP(0);
        MGROUP(1);
        __builtin_amdgcn_s_setprio(0);
        asm volatile("s_waitcnt vmcnt(0)\ns_barrier" ::: "memory");
        if (it + 1 < itN) READF(0, c ^ 1);
    }
#undef ISSUE
#undef READF
#undef MGROUP
}

// ---------------------------------------------------------------------------
// Kernel C: balanced grid of 512 blocks. Each block: 1 full tile (128 iters)
// + one 4-iter K-slice of a leftover tile (16 leftover x 32 slices = 512),
// so every block does exactly 132 iters -> no grid-quantization tail.
// Slice partials accumulate IN K: re at K[i][j], im at mirror K[j][i]
// (diag tiles: only i<j pairs; Hermitian symmetry reconstructs the rest).
// ---------------------------------------------------------------------------
__global__ __launch_bounds__(256, 2) void qnn_gram(const u16* __restrict__ Rm,
                                                   const u16* __restrict__ Im,
                                                   float* __restrict__ K) {
    __shared__ __align__(16) unsigned char lds[2][4][TILE][64];   // 64 KB
    const int t = threadIdx.x;
    const int w = t >> 6, lane = t & 63;
    const int half = lane >> 5, l31 = lane & 31;
    const int wm = (w >> 1) * 64, wn = (w & 1) * 64;

    const int p = blockIdx.x;
    int bi, bj;
    tile_of(p, &bi, &bj);

    f32x16 accRe[2][2], accIm[2][2];
    #pragma unroll
    for (int a = 0; a < 2; ++a)
        #pragma unroll
        for (int b = 0; b < 2; ++b)
            #pragma unroll
            for (int r = 0; r < 16; ++r) { accRe[a][b][r] = 0.f; accIm[a][b][r] = 0.f; }

    gram_accum(Rm, Im, bi * TILE, bj * TILE, 0, NIT, lds, accRe, accIm, w, lane);

    // main-tile epilogue: C/D layout col=lane&31, row=(reg&3)+8*(reg>>2)+4*(lane>>5)
    {
        const int iBase = bi * TILE + wm;
        const int jBase = bj * TILE + wn;
        #pragma unroll
        for (int mi = 0; mi < 2; ++mi)
            #pragma unroll
            for (int ni = 0; ni < 2; ++ni)
                #pragma unroll
                for (int r = 0; r < 16; ++r) {
                    int row32 = (r & 3) + 8 * (r >> 2) + 4 * half;
                    int i = iBase + mi * 32 + row32;
                    int j = jBase + ni * 32 + l31;
                    float re = accRe[mi][ni][r];
                    float im = accIm[mi][ni][r];
                    float v = re * re + im * im;
                    if (i == j) v = 1.0f;
                    K[(size_t)i * BATCH + j] = v;
                    if (bi != bj) K[(size_t)j * BATCH + i] = v;
                }
    }

    // leftover-tile slice: tile lt = p>>5, iters [si*4, si*4+4)
    const int lt = p >> 5;           // 0..15
    const int si = p & 31;           // 0..31
    int bi2, bj2;
    tile_of(NMAIN + lt, &bi2, &bj2);

    #pragma unroll
    for (int a = 0; a < 2; ++a)
        #pragma unroll
        for (int b = 0; b < 2; ++b)
            #pragma unroll
            for (int r = 0; r < 16; ++r) { accRe[a][b][r] = 0.f; accIm[a][b][r] = 0.f; }

    gram_accum(Rm, Im, bi2 * TILE, bj2 * TILE, si * SLICE_IT, (si + 1) * SLICE_IT,
               lds, accRe, accIm, w, lane);

    const bool diag = (bi2 == bj2);
    #pragma unroll
    for (int mi = 0; mi < 2; ++mi)
        #pragma unroll
        for (int ni = 0; ni < 2; ++ni)
            #pragma unroll
            for (int r = 0; r < 16; ++r) {
                int row32 = (r & 3) + 8 * (r >> 2) + 4 * half;
                int il = wm + mi * 32 + row32;
                int jl = wn + ni * 32 + l31;
                if (diag && il >= jl) continue;   // Hermitian: keep only i<j
                int i = bi2 * TILE + il;
                int j = bj2 * TILE + jl;
                atomicAdd(&K[(size_t)i * BATCH + j], accRe[mi][ni][r]);
                atomicAdd(&K[(size_t)j * BATCH + i], accIm[mi][ni][r]);
            }
}

// ---------------------------------------------------------------------------
// Kernel D: square the 16 leftover tiles from their in-K accumulated
// partials: re at K[i][j], im at K[j][i] -> both become re^2+im^2.
// ---------------------------------------------------------------------------
__global__ __launch_bounds__(256) void qnn_fix(float* __restrict__ K) {
    const int t = threadIdx.x, b = blockIdx.x;   // b in 0..15
    int bi, bj;
    tile_of(NMAIN + b, &bi, &bj);
    const bool diag = (bi == bj);
    for (int e = t; e < TILE * TILE; e += 256) {
        const int il = e >> 7, jl = e & 127;
        const int i = bi * TILE + il, j = bj * TILE + jl;
        if (diag) {
            if (il > jl) continue;
            if (il == jl) { K[(size_t)i * BATCH + j] = 1.0f; continue; }
        }
        float re = K[(size_t)i * BATCH + j];
        float im = K[(size_t)j * BATCH + i];
        float v = re * re + im * im;
        K[(size_t)i * BATCH + j] = v;
        K[(size_t)j * BATCH + i] = v;
    }
}

extern "C" void kernel_launch(void* const* d_in, const int* in_sizes, int n_in,
                              void* d_out, int out_size, void* d_ws, size_t ws_size,
                              hipStream_t stream) {
    const float* X = (const float*)d_in[0];
    const float* params = (const float*)d_in[1];

    float2* psi1 = (float2*)d_ws;
    u16* R = (u16*)((char*)d_ws + 65536);
    u16* I = R + (size_t)BATCH * DIM;
    float* K = (float*)d_out;

    hipLaunchKernelGGL(qnn_base, dim3(1), dim3(1024), 0, stream, params, psi1);
    hipLaunchKernelGGL(qnn_states, dim3(BATCH), dim3(1024), 0, stream, X, psi1, R, I, K);
    hipLaunchKernelGGL(qnn_gram, dim3(NMAIN), dim3(256), 0, stream, R, I, K);
    hipLaunchKernelGGL(qnn_fix, dim3(NLEFT), dim3(256), 0, stream, K);
}